// Round 4
// baseline (172.540 us; speedup 1.0000x reference)
//
#include <hip/hip_runtime.h>

#define NN 4096
#define DIN 512
#define DOUT 128
#define NH 4
#define LOG2E 1.44269504088896340736f

typedef __bf16 bf16x8 __attribute__((ext_vector_type(8)));
typedef float f32x4 __attribute__((ext_vector_type(4)));
typedef float f32x16 __attribute__((ext_vector_type(16)));
typedef unsigned short u16;
typedef unsigned int u32;
typedef u16 u16x8 __attribute__((ext_vector_type(8)));
typedef u16 u16x4 __attribute__((ext_vector_type(4)));

static __device__ __forceinline__ u16 f2bf(float f) {
  __bf16 h = (__bf16)f;
  return __builtin_bit_cast(u16, h);
}

// async global->LDS, 16B/lane; dest = wave-uniform base + lane*16
static __device__ __forceinline__ void gl_lds16(const void* g, void* l) {
  __builtin_amdgcn_global_load_lds(
      (const __attribute__((address_space(1))) unsigned int*)g,
      (__attribute__((address_space(3))) unsigned int*)l, 16, 0, 0);
}

// ------- Kernel 0: pack adj into bits (blocks 0..2047) + W^T hi/lo split ----
__global__ __launch_bounds__(256) void pack_prep(const float* __restrict__ adj,
                                                 u32* __restrict__ adjW,
                                                 const float* __restrict__ W,
                                                 u16* __restrict__ wthi,
                                                 u16* __restrict__ wtlo) {
  const int b = blockIdx.x;
  const int t = threadIdx.x;
  if (b < 2048) {
    const int idx = b * 256 + t;               // word index; covers j=32*idx..+31
    const float4* src = (const float4*)(adj + (size_t)idx * 32);
    u32 m = 0;
    #pragma unroll
    for (int c = 0; c < 8; ++c) {
      const float4 v = src[c];
      m |= (v.x != 0.f ? 1u : 0u) << (c * 4);
      m |= (v.y != 0.f ? 2u : 0u) << (c * 4);
      m |= (v.z != 0.f ? 4u : 0u) << (c * 4);
      m |= (v.w != 0.f ? 8u : 0u) << (c * 4);
    }
    adjW[idx] = m;
  } else {
    const int n = b - 2048;
    for (int k = t; k < 512; k += 256) {
      const float w = W[(size_t)k * 128 + n];
      const __bf16 hi = (__bf16)w;
      wthi[(size_t)n * 512 + k] = __builtin_bit_cast(u16, hi);
      wtlo[(size_t)n * 512 + k] = f2bf(w - (float)hi);
    }
  }
}

// ------- Kernel 1: h = x@W (split-bf16 MFMA) -> hT (bf16), el, erT ----------
__global__ __launch_bounds__(512, 1) void hcompute(
    const float* __restrict__ x, const u16* __restrict__ wthi,
    const u16* __restrict__ wtlo, const float* __restrict__ alw,
    const float* __restrict__ arw, u16* __restrict__ hT,
    float* __restrict__ el, float* __restrict__ erT) {
  __shared__ __align__(16) char pool[147456];
  const int t = threadIdx.x;
  const int i0 = blockIdx.x * 16;
  const int lane = t & 63, w = t >> 6;
  const int l15 = lane & 15, lhi = lane >> 4;

  const int xr = t >> 5, xk = (t & 31) * 4;
  const unsigned x_off =
      ((unsigned)(xr * 256 + xk * 2)) ^ ((unsigned)((xr & 7) << 4));

  f32x4 acc = (f32x4){0.f, 0.f, 0.f, 0.f};

  auto stageW = [&](int kc, int buf) {
    #pragma unroll
    for (int q = 0; q < 4; ++q) {
      const int off = q * 8192 + t * 16;
      const int n = off >> 8;
      const int kb = off & 255;
      const int ksrc = (kb ^ ((n & 7) << 4)) >> 1;
      const size_t so = (size_t)n * 512 + kc * 128 + ksrc;
      gl_lds16(wthi + so, pool + 16384 + buf * 32768 + off);
      gl_lds16(wtlo + so, pool + 81920 + buf * 32768 + off);
    }
  };
  auto writeX = [&](const float4& xv, int buf) {
    u16x4 hi, lo;
    const float* xp = (const float*)&xv;
    #pragma unroll
    for (int j = 0; j < 4; ++j) {
      const __bf16 hb = (__bf16)xp[j];
      hi[j] = __builtin_bit_cast(u16, hb);
      lo[j] = f2bf(xp[j] - (float)hb);
    }
    *(u16x4*)(pool + buf * 4096 + x_off) = hi;
    *(u16x4*)(pool + 8192 + buf * 4096 + x_off) = lo;
  };

  stageW(0, 0);
  {
    float4 xv = *(const float4*)(x + (size_t)(i0 + xr) * DIN + xk);
    writeX(xv, 0);
  }
  float4 xnext;
  for (int kc = 0; kc < 4; ++kc) {
    const int cur = kc & 1;
    __syncthreads();
    const bool more = (kc < 3);
    if (more) {
      stageW(kc + 1, cur ^ 1);
      xnext = *(const float4*)(x + (size_t)(i0 + xr) * DIN + (kc + 1) * 128 + xk);
    }
    #pragma unroll
    for (int ks = 0; ks < 4; ++ks) {
      const unsigned kbyte = (unsigned)(ks * 64 + lhi * 16);
      const unsigned xoff =
          (unsigned)(l15 * 256) + (kbyte ^ (unsigned)((l15 & 7) << 4));
      const bf16x8 ah = *(const bf16x8*)(pool + cur * 4096 + xoff);
      const bf16x8 al = *(const bf16x8*)(pool + 8192 + cur * 4096 + xoff);
      const int n = w * 16 + l15;
      const unsigned wb =
          (unsigned)(n * 256) + (kbyte ^ (unsigned)((n & 7) << 4));
      const bf16x8 bh = *(const bf16x8*)(pool + 16384 + cur * 32768 + wb);
      const bf16x8 bl = *(const bf16x8*)(pool + 81920 + cur * 32768 + wb);
      acc = __builtin_amdgcn_mfma_f32_16x16x32_bf16(ah, bh, acc, 0, 0, 0);
      acc = __builtin_amdgcn_mfma_f32_16x16x32_bf16(al, bh, acc, 0, 0, 0);
      acc = __builtin_amdgcn_mfma_f32_16x16x32_bf16(ah, bl, acc, 0, 0, 0);
    }
    if (more) writeX(xnext, cur ^ 1);
  }
  __syncthreads();
  float* h_lds = (float*)(pool + 16384);  // [16][132]
  #pragma unroll
  for (int reg = 0; reg < 4; ++reg)
    h_lds[(lhi * 4 + reg) * 132 + w * 16 + l15] = acc[reg];
  __syncthreads();
  {
    const int d = t >> 2, ih0 = (t & 3) * 4;
    u16x4 hv;
    #pragma unroll
    for (int j = 0; j < 4; ++j) hv[j] = f2bf(h_lds[(ih0 + j) * 132 + d]);
    *(u16x4*)(hT + (size_t)d * NN + i0 + ih0) = hv;
  }
  if (t < 128) {
    const int r = t >> 3, hh = (t >> 1) & 3, side = t & 1;
    const float* wrow = (side ? arw : alw) + hh * DOUT;
    float s = 0.f;
    for (int d = 0; d < 128; ++d) s += h_lds[r * 132 + d] * wrow[d];
    s *= LOG2E;
    if (side == 0) el[(size_t)(i0 + r) * NH + hh] = s;
    else erT[(size_t)hh * NN + i0 + r] = s;
  }
}

// ------- Kernel 2: fused weight-gen(in-reg A frags) + PV GEMM (32x32x16) ----
// Block: 16 graph rows x 4 heads = 64 MFMA rows x 128 cols. 8 waves =
// rt(2: 32-row halves) x kkg(4: 16-k slices). A frags generated in registers
// (no LDS); B (hT tile) in LDS only. kkg-partial accs reduced at epilogue.
__global__ __launch_bounds__(512, 1) void gat_main(
    const unsigned char* __restrict__ adjB, const u16* __restrict__ hT,
    const float* __restrict__ el, const float* __restrict__ erT,
    const float* __restrict__ bias, float* __restrict__ outp) {
  __shared__ __align__(16) char B_lds[2][2][16384];  // [buf][tile][128col x 64k bf16]
  __shared__ float S_lds[64];
  const int t = threadIdx.x;
  const int i0 = blockIdx.x * 16;
  const int lane = t & 63;
  const int w = t >> 6;
  const int rt = (w >> 2) & 1;
  const int kkg = w & 3;
  const int l31 = lane & 31;
  const int lh = lane >> 5;  // 0/1: k-subslice within 16
  const int il = l31 & 15;
  const int head = rt * 2 + (l31 >> 4);
  const float elv = el[(size_t)(i0 + il) * NH + head];
  if (t < 64) S_lds[t] = 0.f;

  // B staging: linear dest (t*16), pre-swizzled source k
  const int bd = t >> 3;
  const int bkb = (t & 7) * 16;
  const u16* hsrc0 = hT + (size_t)bd * NN + (((unsigned)bkb ^ ((bd & 7) << 4)) >> 1);
  const u16* hsrc1 = hsrc0 + (size_t)64 * NN;  // cols 64..127 ((bd+64)&7 == bd&7)
  auto stageB = [&](int tile, char* buf) {
    gl_lds16(hsrc0 + tile * 64, buf + t * 16);
    gl_lds16(hsrc1 + tile * 64, buf + 8192 + t * 16);
  };

  // genA inputs: this lane's A rows = rt*32+l31, k = kkg*16 + lh*8 + q
  const unsigned char* adjp = adjB + (size_t)(i0 + il) * 512 + kkg * 2 + lh;
  const float* erp = erT + (size_t)head * NN + kkg * 16 + lh * 8;
  auto loadInputs = [&](int tile0, float4 (&e0)[2], float4 (&e1)[2], u32 (&ab)[2]) {
    #pragma unroll
    for (int s = 0; s < 2; ++s) {
      e0[s] = *(const float4*)(erp + (tile0 + s) * 64);
      e1[s] = *(const float4*)(erp + (tile0 + s) * 64 + 4);
      ab[s] = adjp[(tile0 + s) * 8];
    }
  };

  f32x16 acc[4];
  #pragma unroll
  for (int ct = 0; ct < 4; ++ct)
    #pragma unroll
    for (int q = 0; q < 16; ++q) acc[ct][q] = 0.f;
  float Sp = 0.f;
  const unsigned kb = (unsigned)(kkg * 32 + lh * 16);

  float4 e0A[2], e1A[2];
  u32 abA[2];
  float4 e0B[2], e1B[2];
  u32 abB[2];
  loadInputs(0, e0A, e1A, abA);
  stageB(0, &B_lds[0][0][0]);
  stageB(1, &B_lds[0][1][0]);

  auto phase = [&](int p, float4 (&ue0)[2], float4 (&ue1)[2], u32 (&uab)[2],
                   float4 (&ne0)[2], float4 (&ne1)[2], u32 (&nab)[2]) {
    const int bp = p & 1;
    __syncthreads();  // buf[bp] staged; buf[bp^1] free; prefetched inputs landed
    if (p < 31) {
      stageB(2 * p + 2, &B_lds[bp ^ 1][0][0]);
      stageB(2 * p + 3, &B_lds[bp ^ 1][1][0]);
      loadInputs(2 * p + 2, ne0, ne1, nab);
    }
    #pragma unroll
    for (int tl = 0; tl < 2; ++tl) {
      float ev[8];
      *(float4*)ev = ue0[tl];
      *(float4*)(ev + 4) = ue1[tl];
      u16x8 pk;
      float s = 0.f;
      #pragma unroll
      for (int q = 0; q < 8; ++q) {
        const float e = elv + ev[q];
        const float lr = fmaxf(e, 0.2f * e);           // lrelu in log2 domain
        const float ex = __builtin_amdgcn_exp2f(lr);
        const int msk = ((int)(uab[tl] << (31 - q))) >> 31;
        const float av =
            __builtin_bit_cast(float, __builtin_bit_cast(int, ex) & msk);
        s += av;
        pk[q] = f2bf(av);
      }
      Sp += s;
      const bf16x8 af = __builtin_bit_cast(bf16x8, pk);
      const char* Bt = &B_lds[bp][tl][0];
      __builtin_amdgcn_s_setprio(1);
      #pragma unroll
      for (int ct = 0; ct < 4; ++ct) {
        const int col = ct * 32 + l31;
        const bf16x8 bfr = *(const bf16x8*)(
            Bt + col * 128 + (kb ^ ((unsigned)(col & 7) << 4)));
        acc[ct] = __builtin_amdgcn_mfma_f32_32x32x16_bf16(af, bfr, acc[ct], 0, 0, 0);
      }
      __builtin_amdgcn_s_setprio(0);
    }
  };

  for (int pp = 0; pp < 16; ++pp) {
    phase(2 * pp, e0A, e1A, abA, e0B, e1B, abB);
    phase(2 * pp + 1, e0B, e1B, abB, e0A, e1A, abA);
  }

  // ---- epilogue: S totals + cross-kkg acc reduction via B_lds ----
  Sp += __shfl_xor(Sp, 32);  // lanes l, l^32 hold same row, different k-slices
  if (lane < 32) atomicAdd(&S_lds[rt * 32 + l31], Sp);

  float* red = (float*)B_lds;  // 64KB = 4 regions x 4096 floats
  auto writeAcc = [&](int r) {
    float* dst = red + r * 4096;
    #pragma unroll
    for (int ct = 0; ct < 4; ++ct)
      #pragma unroll
      for (int q4 = 0; q4 < 4; ++q4) {
        f32x4 v;
        #pragma unroll
        for (int j = 0; j < 4; ++j) v[j] = acc[ct][q4 * 4 + j];
        *(f32x4*)(dst + (ct * 4 + q4) * 256 + lane * 4) = v;
      }
  };
  auto addAcc = [&](int r) {
    const float* srcr = red + r * 4096;
    #pragma unroll
    for (int ct = 0; ct < 4; ++ct)
      #pragma unroll
      for (int q4 = 0; q4 < 4; ++q4) {
        const f32x4 v = *(const f32x4*)(srcr + (ct * 4 + q4) * 256 + lane * 4);
        #pragma unroll
        for (int j = 0; j < 4; ++j) acc[ct][q4 * 4 + j] += v[j];
      }
  };
  __syncthreads();  // all MFMA reads + S atomics done
  if (kkg >= 2) writeAcc(rt * 2 + (kkg - 2));
  __syncthreads();
  if (kkg < 2) addAcc(rt * 2 + kkg);
  __syncthreads();
  if (kkg == 1) writeAcc(rt);
  __syncthreads();
  if (kkg == 0) {
    addAcc(rt);
    #pragma unroll
    for (int ct = 0; ct < 4; ++ct) {
      const int col = ct * 32 + l31;
      const float bb = bias[col];
      #pragma unroll
      for (int reg = 0; reg < 16; ++reg) {
        const int crow = (reg & 3) + 8 * (reg >> 2) + 4 * lh;
        const int mrow = rt * 32 + crow;
        const float inv = 1.f / fmaxf(S_lds[mrow], 1e-12f);
        outp[(size_t)(i0 + (mrow & 15)) * (NH * DOUT) + (mrow >> 4) * DOUT + col] =
            acc[ct][reg] * inv + bb;
      }
    }
  }
}

extern "C" void kernel_launch(void* const* d_in, const int* in_sizes, int n_in,
                              void* d_out, int out_size, void* d_ws, size_t ws_size,
                              hipStream_t stream) {
  const float* adj = (const float*)d_in[0];
  const float* x = (const float*)d_in[1];
  const float* W = (const float*)d_in[2];
  const float* alw = (const float*)d_in[3];
  const float* arw = (const float*)d_in[4];
  const float* bias = (const float*)d_in[5];
  float* out = (float*)d_out;
  char* ws = (char*)d_ws;
  u16* hT = (u16*)ws;                                     // 1 MB
  float* el = (float*)(ws + 0x100000);                    // 64 KB
  float* erT = (float*)(ws + 0x110000);                   // 64 KB
  unsigned char* adjB = (unsigned char*)(ws + 0x120000);  // 2 MB
  u16* wthi = (u16*)(ws + 0x320000);                      // 128 KB
  u16* wtlo = (u16*)(ws + 0x340000);                      // 128 KB

  pack_prep<<<2176, 256, 0, stream>>>(adj, (u32*)adjB, W, wthi, wtlo);
  hcompute<<<256, 512, 0, stream>>>(x, wthi, wtlo, alw, arw, hT, el, erT);
  gat_main<<<256, 512, 0, stream>>>(adjB, hT, el, erT, bias, out);
}